// Round 15
// baseline (290.344 us; speedup 1.0000x reference)
//
#include <hip/hip_runtime.h>
#include <cstdint>
#include <cstddef>

#define Hc   128
#define INc  256
#define Kc   8
#define HP   136          // stage/hf staging row pad (ushorts)
#define HSP  136          // lstm h_sum/h_new staging row pad (ushorts)
#define EPH  136          // lstm gate-partial arrays row pad (ushorts)
#define ZP2  264          // x staging row pad (ushorts)
#define HCS  384          // HCF interleaved row stride (ushorts): [H|C|F]

typedef unsigned short ushortT;
typedef __attribute__((ext_vector_type(8))) short bf16x8;
typedef __attribute__((ext_vector_type(4))) float f32x4;
typedef __attribute__((ext_vector_type(4))) unsigned short us4;
typedef __attribute__((ext_vector_type(8))) unsigned short us8;

__device__ __forceinline__ void nt_store4(const float* src, float* dst) {
  __builtin_nontemporal_store(*(const f32x4*)src, (f32x4*)dst);
}

__device__ __forceinline__ float fsig(float x) {
  return __builtin_amdgcn_rcpf(1.f + __expf(-x));
}
__device__ __forceinline__ float ftanh(float x) {
  float e = __expf(2.f * fminf(x, 15.f));
  return (e - 1.f) * __builtin_amdgcn_rcpf(e + 1.f);
}
__device__ __forceinline__ ushortT f2bf(float f) {
  unsigned u = __builtin_bit_cast(unsigned, f);
  unsigned r = (u + 0x7fffu + ((u >> 16) & 1u)) >> 16;
  return (ushortT)r;
}
__device__ __forceinline__ us4 f2bf4(float4 v) {
  us4 o; o[0] = f2bf(v.x); o[1] = f2bf(v.y); o[2] = f2bf(v.z); o[3] = f2bf(v.w);
  return o;
}
__device__ __forceinline__ us8 f2bf8(float4 a, float4 b) {
  us8 o;
  o[0] = f2bf(a.x); o[1] = f2bf(a.y); o[2] = f2bf(a.z); o[3] = f2bf(a.w);
  o[4] = f2bf(b.x); o[5] = f2bf(b.y); o[6] = f2bf(b.z); o[7] = f2bf(b.w);
  return o;
}
__device__ __forceinline__ float bf2f(ushortT u) {
  return __builtin_bit_cast(float, (unsigned)u << 16);
}

#define GATE_FRAGS (4*8*12*64)
#define WN_FRAGS   (8*8*64)

// ---------------- kernel 1: init marks ----------------
__global__ void marks_init(int* __restrict__ mark, int M, int* __restrict__ nmark, int NN) {
  int i = blockIdx.x * blockDim.x + threadIdx.x;
  if (i < M) mark[i] = -1;
  if (i < NN) nmark[i] = -1;
}

// ---------------- kernel 2: set marks || repack weights ----------------
__global__ void set_repack(const int* __restrict__ submess, const int* __restrict__ subnode,
                           int S, int* __restrict__ mark, int* __restrict__ nmark,
                           const float* __restrict__ Wi, const float* __restrict__ Wo,
                           const float* __restrict__ Wu, const float* __restrict__ Wf,
                           const float* __restrict__ Wn, ushortT* __restrict__ pack, int SB) {
  if ((int)blockIdx.x < SB) {
    int i = blockIdx.x * 256 + threadIdx.x;
    if (i < S) { mark[submess[i]] = i; nmark[subnode[i]] = i; }
    return;
  }
  int idx = (blockIdx.x - SB) * 256 + threadIdx.x;
  if (idx < GATE_FRAGS) {
    int lane = idx & 63;
    int kt = (idx >> 6) % 12;
    int gc = idx / (64 * 12);
    int c = gc & 7, g = gc >> 3;
    const float* W = (g == 0) ? Wi : (g == 1) ? Wo : (g == 2) ? Wu : Wf;
    int k0 = kt * 32 + (lane >> 4) * 8;
    int col = c * 16 + (lane & 15);
    ushortT* dst = pack + (size_t)idx * 8;
    #pragma unroll
    for (int j = 0; j < 8; ++j) dst[j] = f2bf(W[(size_t)(k0 + j) * Hc + col]);
  } else if (idx < GATE_FRAGS + WN_FRAGS) {
    int i2 = idx - GATE_FRAGS;
    int lane = i2 & 63;
    int kt = (i2 >> 6) & 7;
    int c = i2 >> 9;
    int k0 = kt * 32 + (lane >> 4) * 8;
    int col = c * 16 + (lane & 15);
    ushortT* dst = pack + (size_t)GATE_FRAGS * 8 + (size_t)i2 * 8;
    #pragma unroll
    for (int j = 0; j < 8; ++j) dst[j] = f2bf(Wn[(size_t)(k0 + j) * Hc + col]);
  }
}

// gate B-fragment helpers (kt 0..7 = x-part, kt 8..11 = h-part)
__device__ __forceinline__ const bf16x8* g_frag(const ushortT* pack, int g, int cw, int kt, int lane) {
  return (const bf16x8*)&pack[(size_t)(((g * 8 + cw) * 12 + kt) * 64 + lane) * 8];
}
__device__ __forceinline__ const bf16x8* wh_frag(const ushortT* pack, int g, int cw, int kf, int lane) {
  return (const bf16x8*)&pack[(size_t)(((g * 8 + cw) * 12 + (8 + kf)) * 64 + lane) * 8];
}

// ---------------- kernel 3: stage+Hf tiles (blocks [0,SB)) || fmess->X16 conv ----
__global__ __launch_bounds__(256) void stage_hf_xconv(
    const float* __restrict__ h_in, const float* __restrict__ c_in,
    const int* __restrict__ mark,
    float* __restrict__ h_out, float* __restrict__ c_out,
    ushortT* __restrict__ HCF,
    const float* __restrict__ fmess, const int* __restrict__ submess,
    ushortT* __restrict__ X16,
    const ushortT* __restrict__ pack, int M, int S, int SB)
{
  __shared__ __align__(16) ushortT zh[16 * HP];
  __shared__ int aux[16];
  const int t = threadIdx.x;
  const int w = t >> 6, lane = t & 63, lg = lane >> 4, cl = lane & 15;

  if ((int)blockIdx.x < SB) {
    // ---- stage + Hf tile: 16 rows ----
    const int row0 = blockIdx.x * 16;
    if (blockIdx.x == 0 && t < 48) {    // zero DUMMY row (M+S)
      us8 z;
      #pragma unroll
      for (int e = 0; e < 8; ++e) z[e] = 0;
      *(us8*)&HCF[(size_t)(M + S) * HCS + t * 8] = z;
    }
    if (t < 16) aux[t] = (row0 + t < M) ? mark[row0 + t] : 0;   // >=0 => skip
    __syncthreads();
    {
      int r = t >> 4, cp = t & 15;
      int j = row0 + r;
      us8 hz;
      #pragma unroll
      for (int e = 0; e < 8; ++e) hz[e] = 0;
      if (j < M && aux[r] < 0) {
        const float4* h4 = (const float4*)(h_in + (size_t)j * Hc);
        const float4* c4 = (const float4*)(c_in + (size_t)j * Hc);
        float4 a0 = h4[cp * 2], a1 = h4[cp * 2 + 1];
        float4 b0 = c4[cp * 2], b1 = c4[cp * 2 + 1];
        nt_store4(&a0.x, h_out + (size_t)j * Hc + cp * 8);
        nt_store4(&a1.x, h_out + (size_t)j * Hc + cp * 8 + 4);
        nt_store4(&b0.x, c_out + (size_t)j * Hc + cp * 8);
        nt_store4(&b1.x, c_out + (size_t)j * Hc + cp * 8 + 4);
        us8 h8 = f2bf8(a0, a1);
        *(us8*)&HCF[(size_t)j * HCS + cp * 8] = h8;
        *(us8*)&HCF[(size_t)j * HCS + 128 + cp * 8] = f2bf8(b0, b1);
        hz = h8;
      }
      *(us8*)&zh[r * HP + cp * 8] = hz;
    }
    __syncthreads();

    f32x4 acc0 = (f32x4){0.f,0.f,0.f,0.f}, acc1 = acc0;
    const ushortT* zr = &zh[cl * HP + lg * 8];
    #pragma unroll
    for (int kf = 0; kf < 4; ++kf) {
      bf16x8 a = *(const bf16x8*)&zr[kf * 32];
      acc0 = __builtin_amdgcn_mfma_f32_16x16x32_bf16(a, *wh_frag(pack, 3, w*2+0, kf, lane), acc0, 0, 0, 0);
      acc1 = __builtin_amdgcn_mfma_f32_16x16x32_bf16(a, *wh_frag(pack, 3, w*2+1, kf, lane), acc1, 0, 0, 0);
    }
    __syncthreads();   // zh A-frag reads done; reuse for Hf roundtrip
    #pragma unroll
    for (int half = 0; half < 2; ++half) {
      int col = (w * 2 + half) * 16 + cl;
      f32x4 a_ = half ? acc1 : acc0;
      #pragma unroll
      for (int reg = 0; reg < 4; ++reg)
        zh[(lg * 4 + reg) * HP + col] = f2bf(a_[reg]);
    }
    __syncthreads();
    {
      int r = t >> 4, cp = t & 15;
      if (row0 + r < M && aux[r] < 0)
        *(us8*)&HCF[(size_t)(row0 + r) * HCS + 256 + cp * 8] = *(const us8*)&zh[r * HP + cp * 8];
    }
    return;
  }

  // ---- xconv part: X16[s] = bf16(fmess[submess[s]]) ----
  const int row0 = (blockIdx.x - SB) * 16;
  if (t < 16) aux[t] = (row0 + t < S) ? submess[row0 + t] : -1;
  __syncthreads();
  {
    int r = t >> 4, cp = t & 15;
    int s = row0 + r;
    int ms = aux[r];
    if (ms >= 0) {
      const float4* xr = (const float4*)(fmess + (size_t)ms * INc + cp * 16);
      float4 v0 = xr[0], v1 = xr[1], v2 = xr[2], v3 = xr[3];
      *(us8*)&X16[(size_t)s * INc + cp * 16] = f2bf8(v0, v1);
      *(us8*)&X16[(size_t)s * INc + cp * 16 + 8] = f2bf8(v2, v3);
    }
  }
}

// ---- kernels 4/5: LSTM step, full-K gates from X16 (no Xg intermediate) ----
// MODE 0: sub neighbors -> DUMMY zero row; writes HCF[M+spos] H/C, partials,
//         fused Hf tail. MODE 1: sub -> M+mark, non-sub -> DUMMY; final f32 out.
template<int MODE>
__global__ __launch_bounds__(256) void lstm9(
    const int* __restrict__ submess, const int* __restrict__ bgraph,
    const int* __restrict__ mark,
    ushortT* HCF, const ushortT* __restrict__ X16,
    const ushortT* __restrict__ pack,
    const float* __restrict__ bi, const float* __restrict__ bo,
    const float* __restrict__ bu, const float* __restrict__ bfb,
    ushortT* hsumNS, ushortT* cpartNS,
    float* __restrict__ dstH, float* __restrict__ dstC, int S, int M)
{
  __shared__ __align__(16) ushortT zs[16 * HSP];    // h_sum; reused for h_new (MODE 0)
  __shared__ __align__(16) ushortT xs[16 * ZP2];    // x bf16
  __shared__ __align__(16) ushortT pih[16 * EPH];
  __shared__ __align__(16) ushortT poh[16 * EPH];
  __shared__ __align__(16) ushortT puh[16 * EPH];
  __shared__ __align__(16) ushortT pfh[16 * EPH];
  __shared__ int nbj[16][Kc];
  __shared__ int msrow[16];

  const int t = threadIdx.x;
  const int row0 = blockIdx.x * 16;
  const int DUMMY = M + S;

  if (t < 128) {
    int r = t >> 3, k = t & 7;
    int s = row0 + r;
    int ms = (s < S) ? submess[s] : -1;
    if (k == 0) msrow[r] = ms;
    int j = DUMMY;
    if (ms >= 0) {
      int jj = bgraph[(size_t)ms * Kc + k];
      int m = mark[jj];
      j = (MODE == 0) ? (m >= 0 ? DUMMY : jj) : (m >= 0 ? M + m : DUMMY);
    }
    nbj[r][k] = j;
  }
  __syncthreads();

  // ---- stage x + h_sum gather ----
  {
    int r = t >> 4, cp = t & 15;
    int spos = row0 + r;
    // x (bf16, precomputed)
    {
      size_t sidx = (size_t)((spos < S) ? spos : 0) * INc + cp * 16;
      const us8* xr = (const us8*)&X16[sidx];
      *(us8*)&xs[r * ZP2 + cp * 16] = xr[0];
      *(us8*)&xs[r * ZP2 + cp * 16 + 8] = xr[1];
    }
    // h_sum (MODE 1 seeded with saved non-sub partial)
    float sum[8] = {0.f,0.f,0.f,0.f,0.f,0.f,0.f,0.f};
    if (MODE == 1 && spos < S) {
      us8 hs = *(const us8*)&hsumNS[(size_t)spos * Hc + cp * 8];
      #pragma unroll
      for (int e = 0; e < 8; ++e) sum[e] = bf2f(hs[e]);
    }
    #pragma unroll
    for (int k = 0; k < Kc; ++k) {
      int j = nbj[r][k];
      us8 v = *(const us8*)&HCF[(size_t)j * HCS + cp * 8];
      #pragma unroll
      for (int e = 0; e < 8; ++e) sum[e] += bf2f(v[e]);
    }
    us8 o8;
    #pragma unroll
    for (int e = 0; e < 8; ++e) o8[e] = f2bf(sum[e]);
    *(us8*)&zs[r * HSP + cp * 8] = o8;
    if (MODE == 0 && spos < S)
      *(us8*)&hsumNS[(size_t)spos * Hc + cp * 8] = o8;
  }
  __syncthreads();

  const int w = t >> 6, lane = t & 63, lg = lane >> 4, cl = lane & 15;

  // ---- full-K gate loop: x-part (8 kt x 8 accs) + h-part (4 kt x 6 accs) = 88 MFMAs
  f32x4 acc[8];   // {i0,i1,o0,o1,u0,u1,f0,f1}
  #pragma unroll
  for (int i = 0; i < 8; ++i) acc[i] = (f32x4){0.f, 0.f, 0.f, 0.f};
  const ushortT* xrow = &xs[cl * ZP2 + lg * 8];
  const ushortT* zrow = &zs[cl * HSP + lg * 8];
  #pragma unroll
  for (int kt = 0; kt < 8; ++kt) {
    bf16x8 a = *(const bf16x8*)&xrow[kt * 32];
    #pragma unroll
    for (int tix = 0; tix < 8; ++tix) {
      int g = tix >> 1, cw = w * 2 + (tix & 1);
      acc[tix] = __builtin_amdgcn_mfma_f32_16x16x32_bf16(
          a, *g_frag(pack, g, cw, kt, lane), acc[tix], 0, 0, 0);
    }
  }
  #pragma unroll
  for (int kf = 0; kf < 4; ++kf) {
    bf16x8 a = *(const bf16x8*)&zrow[kf * 32];
    #pragma unroll
    for (int tix = 0; tix < 6; ++tix) {   // i,o,u only (f's h-part is per-neighbor)
      int g = tix >> 1, cw = w * 2 + (tix & 1);
      acc[tix] = __builtin_amdgcn_mfma_f32_16x16x32_bf16(
          a, *wh_frag(pack, g, cw, kf, lane), acc[tix], 0, 0, 0);
    }
  }

  // ---- write gate partials (disjoint LDS arrays) ----
  #pragma unroll
  for (int half = 0; half < 2; ++half) {
    int col = (w * 2 + half) * 16 + cl;
    #pragma unroll
    for (int reg = 0; reg < 4; ++reg) {
      int row = lg * 4 + reg;
      pih[row * EPH + col] = f2bf(acc[0 + half][reg]);
      poh[row * EPH + col] = f2bf(acc[2 + half][reg]);
      puh[row * EPH + col] = f2bf(acc[4 + half][reg]);
      pfh[row * EPH + col] = f2bf(acc[6 + half][reg]);
    }
  }
  __syncthreads();

  // ---- epilogue: (row, 8-col chunk) ----
  {
    int r = t >> 4, cc = t & 15;
    int ms = msrow[r];
    int spos = row0 + r;
    us8 pi8 = *(const us8*)&pih[r * EPH + cc * 8];
    us8 po8 = *(const us8*)&poh[r * EPH + cc * 8];
    us8 pu8 = *(const us8*)&puh[r * EPH + cc * 8];
    us8 pf8 = *(const us8*)&pfh[r * EPH + cc * 8];
    float bia[8], boa[8], bua[8], bfa[8];
    {
      *(float4*)&bia[0] = ((const float4*)(bi + cc * 8))[0];
      *(float4*)&bia[4] = ((const float4*)(bi + cc * 8))[1];
      *(float4*)&boa[0] = ((const float4*)(bo + cc * 8))[0];
      *(float4*)&boa[4] = ((const float4*)(bo + cc * 8))[1];
      *(float4*)&bua[0] = ((const float4*)(bu + cc * 8))[0];
      *(float4*)&bua[4] = ((const float4*)(bu + cc * 8))[1];
      *(float4*)&bfa[0] = ((const float4*)(bfb + cc * 8))[0];
      *(float4*)&bfa[4] = ((const float4*)(bfb + cc * 8))[1];
    }
    float fx[8], ovv[8], iu[8], cn[8];
    #pragma unroll
    for (int e = 0; e < 8; ++e) {
      float iv = fsig(bf2f(pi8[e]) + bia[e]);
      float uv = ftanh(bf2f(pu8[e]) + bua[e]);
      ovv[e] = fsig(bf2f(po8[e]) + boa[e]);
      fx[e] = bf2f(pf8[e]) + bfa[e];
      iu[e] = iv * uv;
      cn[e] = 0.f;
    }
    #pragma unroll
    for (int k = 0; k < Kc; ++k) {
      int j = nbj[r][k];
      us8 hf8 = *(const us8*)&HCF[(size_t)j * HCS + 256 + cc * 8];
      us8 cn8 = *(const us8*)&HCF[(size_t)j * HCS + 128 + cc * 8];
      #pragma unroll
      for (int e = 0; e < 8; ++e)
        cn[e] = fmaf(fsig(fx[e] + bf2f(hf8[e])), bf2f(cn8[e]), cn[e]);
    }
    float cacc[8];
    if (MODE == 1 && spos < S) {
      us8 cp8 = *(const us8*)&cpartNS[(size_t)spos * Hc + cc * 8];
      #pragma unroll
      for (int e = 0; e < 8; ++e) cacc[e] = iu[e] + cn[e] + bf2f(cp8[e]);
    } else {
      #pragma unroll
      for (int e = 0; e < 8; ++e) cacc[e] = iu[e] + cn[e];
    }
    float hv[8];
    #pragma unroll
    for (int e = 0; e < 8; ++e) hv[e] = ovv[e] * ftanh(cacc[e]);

    if (MODE == 0) {
      us8 h8, c8, cn16;
      #pragma unroll
      for (int e = 0; e < 8; ++e) {
        h8[e] = (spos < S) ? f2bf(hv[e]) : (ushortT)0;
        c8[e] = f2bf(cacc[e]);
        cn16[e] = f2bf(cn[e]);
      }
      if (spos < S) {
        *(us8*)&HCF[(size_t)(M + spos) * HCS + cc * 8] = h8;
        *(us8*)&HCF[(size_t)(M + spos) * HCS + 128 + cc * 8] = c8;
        *(us8*)&cpartNS[(size_t)spos * Hc + cc * 8] = cn16;
      }
      *(us8*)&zs[r * HSP + cc * 8] = h8;
    } else {
      if (ms >= 0) {
        float* dh = dstH + (size_t)ms * Hc + cc * 8;
        float* dc = dstC + (size_t)ms * Hc + cc * 8;
        *(float4*)&dh[0] = *(float4*)&hv[0];
        *(float4*)&dh[4] = *(float4*)&hv[4];
        nt_store4(&cacc[0], &dc[0]);
        nt_store4(&cacc[4], &dc[4]);
      }
    }
  }

  if (MODE == 0) {
    // ---- fused Hf tail; stores via pih roundtrip -> HCF[M+sp].F ----
    __syncthreads();
    f32x4 a0 = (f32x4){0.f,0.f,0.f,0.f}, a1 = a0;
    const ushortT* zr2 = &zs[cl * HSP + lg * 8];
    #pragma unroll
    for (int kf = 0; kf < 4; ++kf) {
      bf16x8 a = *(const bf16x8*)&zr2[kf * 32];
      a0 = __builtin_amdgcn_mfma_f32_16x16x32_bf16(a, *wh_frag(pack, 3, w*2+0, kf, lane), a0, 0, 0, 0);
      a1 = __builtin_amdgcn_mfma_f32_16x16x32_bf16(a, *wh_frag(pack, 3, w*2+1, kf, lane), a1, 0, 0, 0);
    }
    #pragma unroll
    for (int half = 0; half < 2; ++half) {
      int col = (w * 2 + half) * 16 + cl;
      f32x4 a_ = half ? a1 : a0;
      #pragma unroll
      for (int reg = 0; reg < 4; ++reg)
        pih[(lg * 4 + reg) * EPH + col] = f2bf(a_[reg]);
    }
    __syncthreads();
    {
      int r = t >> 4, cp = t & 15;
      int sp = row0 + r;
      if (sp < S)
        *(us8*)&HCF[(size_t)(M + sp) * HCS + 256 + cp * 8] = *(const us8*)&pih[r * EPH + cp * 8];
    }
  }
}

// ---------------- kernel 6: node readout || zero non-sub node rows ----------------
__global__ __launch_bounds__(256) void readout_zero(
    const float* __restrict__ fnode, const int* __restrict__ agraph,
    const int* __restrict__ subnode, const float* __restrict__ h_out,
    const ushortT* __restrict__ HCF, const int* __restrict__ mark,
    const int* __restrict__ nmark,
    const ushortT* __restrict__ packWn, const float* __restrict__ bn,
    float* __restrict__ node_buf, int Nsub, int num_nodes, int NB, int ZB)
{
  __shared__ __align__(16) ushortT z2[16 * ZP2];
  __shared__ int orow[16];
  __shared__ int jn[16][Kc];

  const int t = threadIdx.x;

  if ((int)blockIdx.x >= NB) {
    long total = (long)num_nodes * 16;
    float zbuf[4] = {0.f, 0.f, 0.f, 0.f};
    for (long idx = (long)(blockIdx.x - NB) * 256 + t; idx < total; idx += (long)ZB * 256) {
      long v = idx >> 4;
      int cp = (int)(idx & 15);
      if (nmark[v] < 0) {
        nt_store4(zbuf, node_buf + (size_t)v * Hc + cp * 8);
        nt_store4(zbuf, node_buf + (size_t)v * Hc + cp * 8 + 4);
      }
    }
    return;
  }

  const int row0 = blockIdx.x * 16;
  if (t < 16) orow[t] = (row0 + t < Nsub) ? subnode[row0 + t] : -1;
  if (t >= 64 && t < 64 + 128) {
    int i = t - 64, r = i >> 3, k = i & 7;
    int v = row0 + r;
    int j = 0;
    if (v < Nsub) {
      j = agraph[(size_t)v * Kc + k];
      if (mark[j] >= 0) j = ~j;   // sub message: gather f32 from h_out
    }
    jn[r][k] = j;
  }
  {
    int r = t >> 4, cp = t & 15;
    int v = row0 + r;
    const float4* fr = (v < Nsub) ? (const float4*)(fnode + (size_t)v * Hc) : nullptr;
    float4 v0, v1; v0.x = v0.y = v0.z = v0.w = 0.f; v1 = v0;
    if (fr) { v0 = fr[cp]; v1 = fr[cp + 16]; }
    *(us4*)&z2[r * ZP2 + cp * 4] = f2bf4(v0);
    *(us4*)&z2[r * ZP2 + 64 + cp * 4] = f2bf4(v1);
  }
  __syncthreads();
  {
    int r = t >> 4, cp = t & 15;
    float sum[8] = {0.f,0.f,0.f,0.f,0.f,0.f,0.f,0.f};
    #pragma unroll
    for (int k = 0; k < Kc; ++k) {
      int je = jn[r][k];
      if (je < 0) {
        int j = ~je;
        float4 p0 = ((const float4*)(h_out + (size_t)j * Hc))[cp * 2];
        float4 p1 = ((const float4*)(h_out + (size_t)j * Hc))[cp * 2 + 1];
        sum[0] += p0.x; sum[1] += p0.y; sum[2] += p0.z; sum[3] += p0.w;
        sum[4] += p1.x; sum[5] += p1.y; sum[6] += p1.z; sum[7] += p1.w;
      } else {
        us8 v = *(const us8*)&HCF[(size_t)je * HCS + cp * 8];
        #pragma unroll
        for (int e = 0; e < 8; ++e) sum[e] += bf2f(v[e]);
      }
    }
    us8 o8;
    #pragma unroll
    for (int e = 0; e < 8; ++e) o8[e] = f2bf(sum[e]);
    *(us8*)&z2[r * ZP2 + Hc + cp * 8] = o8;
  }
  __syncthreads();

  const int w = t >> 6, lane = t & 63;
  const int lg = lane >> 4, cl = lane & 15;

  f32x4 acc0 = (f32x4){0.f,0.f,0.f,0.f};
  f32x4 acc1 = (f32x4){0.f,0.f,0.f,0.f};
  const ushortT* zr = &z2[cl * ZP2 + lg * 8];
  #pragma unroll
  for (int kt = 0; kt < 8; ++kt) {
    bf16x8 a = *(const bf16x8*)&zr[kt * 32];
    bf16x8 b0 = *(const bf16x8*)&packWn[(size_t)(((w * 2 + 0) * 8 + kt) * 64 + lane) * 8];
    bf16x8 b1 = *(const bf16x8*)&packWn[(size_t)(((w * 2 + 1) * 8 + kt) * 64 + lane) * 8];
    acc0 = __builtin_amdgcn_mfma_f32_16x16x32_bf16(a, b0, acc0, 0, 0, 0);
    acc1 = __builtin_amdgcn_mfma_f32_16x16x32_bf16(a, b1, acc1, 0, 0, 0);
  }
  __syncthreads();   // z2 A-frag reads done; reuse as f32 output buffer
  float* zf = (float*)z2;   // [16][132] f32
  #pragma unroll
  for (int half = 0; half < 2; ++half) {
    int col = (w * 2 + half) * 16 + cl;
    float bnv = bn[col];
    f32x4 a_ = half ? acc1 : acc0;
    #pragma unroll
    for (int reg = 0; reg < 4; ++reg)
      zf[(lg * 4 + reg) * 132 + col] = fmaxf(a_[reg] + bnv, 0.f);
  }
  __syncthreads();
  {
    int r = t >> 4, cc = t & 15;
    int o = orow[r];
    if (o >= 0) {
      float* dst = node_buf + (size_t)o * Hc + cc * 8;
      nt_store4(&zf[r * 132 + cc * 8], &dst[0]);
      nt_store4(&zf[r * 132 + cc * 8 + 4], &dst[4]);
    }
  }
}

// ---------------- launch ----------------
extern "C" void kernel_launch(void* const* d_in, const int* in_sizes, int n_in,
                              void* d_out, int out_size, void* d_ws, size_t ws_size,
                              hipStream_t stream) {
  const float* fnode   = (const float*)d_in[0];
  const float* fmess   = (const float*)d_in[1];
  const int*   agraph  = (const int*)d_in[2];
  const int*   bgraph  = (const int*)d_in[3];
  const float* h_in    = (const float*)d_in[4];
  const float* c_in    = (const float*)d_in[5];
  const int*   submess = (const int*)d_in[6];
  const int*   subnode = (const int*)d_in[7];
  const float* Wi = (const float*)d_in[9];
  const float* bi = (const float*)d_in[10];
  const float* Wo = (const float*)d_in[11];
  const float* bo = (const float*)d_in[12];
  const float* Wf = (const float*)d_in[13];
  const float* bf_ = (const float*)d_in[14];
  const float* Wu = (const float*)d_in[15];
  const float* bu = (const float*)d_in[16];
  const float* Wn = (const float*)d_in[17];
  const float* bn = (const float*)d_in[18];

  const int S    = in_sizes[6];
  const int Nsub = in_sizes[2] / Kc;
  const int M    = in_sizes[4] / Hc;
  const int num_nodes = out_size / Hc - 2 * M;

  float* node_buf = (float*)d_out;
  float* h_out = node_buf + (size_t)num_nodes * Hc;
  float* c_out = h_out + (size_t)M * Hc;

  const int lblocks = (S + 15) / 16;

  // ws: mark[M] | nmark[num_nodes] | pack | HCF[(M+S+1)*384] | X16[lblocks*16*256]
  int* mark = (int*)d_ws;
  size_t off = (((size_t)M * sizeof(int)) + 255) & ~(size_t)255;
  int* nmark = (int*)((char*)d_ws + off);
  off += (((size_t)num_nodes * sizeof(int)) + 255) & ~(size_t)255;
  ushortT* pack = (ushortT*)((char*)d_ws + off);
  off += (((size_t)(GATE_FRAGS + WN_FRAGS) * 8 * sizeof(ushortT)) + 255) & ~(size_t)255;
  ushortT* HCF = (ushortT*)((char*)d_ws + off);
  off += (((size_t)(M + S + 1) * HCS * sizeof(ushortT)) + 255) & ~(size_t)255;
  ushortT* X16 = (ushortT*)((char*)d_ws + off);
  ushortT* packWn = pack + (size_t)GATE_FRAGS * 8;
  ushortT* cpartNS = (ushortT*)node_buf;
  ushortT* hsumNS  = cpartNS + (size_t)S * Hc;

  // 1. init marks
  int initN = (M > num_nodes) ? M : num_nodes;
  hipLaunchKernelGGL(marks_init, dim3((initN + 255) / 256), dim3(256), 0, stream,
                     mark, M, nmark, num_nodes);
  // 2. set marks || repack
  {
    int SB = (S + 255) / 256;
    int RB = (GATE_FRAGS + WN_FRAGS + 255) / 256;
    hipLaunchKernelGGL(set_repack, dim3(SB + RB), dim3(256), 0, stream,
                       submess, subnode, S, mark, nmark, Wi, Wo, Wu, Wf, Wn, pack, SB);
  }
  // 3. stage+Hf tiles || fmess->X16 conversion
  {
    int SB2 = (M + 15) / 16;
    hipLaunchKernelGGL(stage_hf_xconv, dim3(SB2 + lblocks), dim3(256), 0, stream,
                       h_in, c_in, mark, h_out, c_out, HCF,
                       fmess, submess, X16, pack, M, S, SB2);
  }
  // 4. iter 0 (fused Hf tail)
  hipLaunchKernelGGL(lstm9<0>, dim3(lblocks), dim3(256), 0, stream,
      submess, bgraph, mark, HCF, X16, pack, bi, bo, bu, bf_,
      hsumNS, cpartNS, h_out, c_out, S, M);
  // 5. iter 1
  hipLaunchKernelGGL(lstm9<1>, dim3(lblocks), dim3(256), 0, stream,
      submess, bgraph, mark, HCF, X16, pack, bi, bo, bu, bf_,
      hsumNS, cpartNS, h_out, c_out, S, M);
  // 6. readout || zero non-sub node rows
  {
    int NB = (Nsub + 15) / 16;
    int ZB = 512;
    hipLaunchKernelGGL(readout_zero, dim3(NB + ZB), dim3(256), 0, stream,
        fnode, agraph, subnode, h_out, HCF, mark, nmark, packWn, bn,
        node_buf, Nsub, num_nodes, NB, ZB);
  }
}

// Round 16
// 271.822 us; speedup vs baseline: 1.0681x; 1.0681x over previous
//
#include <hip/hip_runtime.h>
#include <cstdint>
#include <cstddef>

#define Hc   128
#define INc  256
#define Kc   8
#define HP   136          // stage/hf staging row pad (ushorts)
#define HSP  136          // lstm h_sum/h_new staging row pad (ushorts)
#define EPH  136          // lstm gate-partial arrays row pad (ushorts)
#define ZP2  264          // node/x staging row pad (ushorts)
#define XOP  520          // xg output LDS row pad (ushorts)
#define HCS  384          // HCF interleaved row stride (ushorts): [H|C|F]

typedef unsigned short ushortT;
typedef __attribute__((ext_vector_type(8))) short bf16x8;
typedef __attribute__((ext_vector_type(4))) float f32x4;
typedef __attribute__((ext_vector_type(4))) unsigned short us4;
typedef __attribute__((ext_vector_type(8))) unsigned short us8;

__device__ __forceinline__ void nt_store4(const float* src, float* dst) {
  __builtin_nontemporal_store(*(const f32x4*)src, (f32x4*)dst);
}

__device__ __forceinline__ float fsig(float x) {
  return __builtin_amdgcn_rcpf(1.f + __expf(-x));
}
__device__ __forceinline__ float ftanh(float x) {
  float e = __expf(2.f * fminf(x, 15.f));
  return (e - 1.f) * __builtin_amdgcn_rcpf(e + 1.f);
}
__device__ __forceinline__ ushortT f2bf(float f) {
  unsigned u = __builtin_bit_cast(unsigned, f);
  unsigned r = (u + 0x7fffu + ((u >> 16) & 1u)) >> 16;
  return (ushortT)r;
}
__device__ __forceinline__ us4 f2bf4(float4 v) {
  us4 o; o[0] = f2bf(v.x); o[1] = f2bf(v.y); o[2] = f2bf(v.z); o[3] = f2bf(v.w);
  return o;
}
__device__ __forceinline__ us8 f2bf8(float4 a, float4 b) {
  us8 o;
  o[0] = f2bf(a.x); o[1] = f2bf(a.y); o[2] = f2bf(a.z); o[3] = f2bf(a.w);
  o[4] = f2bf(b.x); o[5] = f2bf(b.y); o[6] = f2bf(b.z); o[7] = f2bf(b.w);
  return o;
}
__device__ __forceinline__ float bf2f(ushortT u) {
  return __builtin_bit_cast(float, (unsigned)u << 16);
}

#define GATE_FRAGS (4*8*12*64)
#define WN_FRAGS   (8*8*64)

// ---------------- kernel 1: init marks ----------------
__global__ void marks_init(int* __restrict__ mark, int M, int* __restrict__ nmark, int NN) {
  int i = blockIdx.x * blockDim.x + threadIdx.x;
  if (i < M) mark[i] = -1;
  if (i < NN) nmark[i] = -1;
}

// ---------------- kernel 2: set marks || repack weights ----------------
__global__ void set_repack(const int* __restrict__ submess, const int* __restrict__ subnode,
                           int S, int* __restrict__ mark, int* __restrict__ nmark,
                           const float* __restrict__ Wi, const float* __restrict__ Wo,
                           const float* __restrict__ Wu, const float* __restrict__ Wf,
                           const float* __restrict__ Wn, ushortT* __restrict__ pack, int SB) {
  if ((int)blockIdx.x < SB) {
    int i = blockIdx.x * 256 + threadIdx.x;
    if (i < S) { mark[submess[i]] = i; nmark[subnode[i]] = i; }
    return;
  }
  int idx = (blockIdx.x - SB) * 256 + threadIdx.x;
  if (idx < GATE_FRAGS) {
    int lane = idx & 63;
    int kt = (idx >> 6) % 12;
    int gc = idx / (64 * 12);
    int c = gc & 7, g = gc >> 3;
    const float* W = (g == 0) ? Wi : (g == 1) ? Wo : (g == 2) ? Wu : Wf;
    int k0 = kt * 32 + (lane >> 4) * 8;
    int col = c * 16 + (lane & 15);
    ushortT* dst = pack + (size_t)idx * 8;
    #pragma unroll
    for (int j = 0; j < 8; ++j) dst[j] = f2bf(W[(size_t)(k0 + j) * Hc + col]);
  } else if (idx < GATE_FRAGS + WN_FRAGS) {
    int i2 = idx - GATE_FRAGS;
    int lane = i2 & 63;
    int kt = (i2 >> 6) & 7;
    int c = i2 >> 9;
    int k0 = kt * 32 + (lane >> 4) * 8;
    int col = c * 16 + (lane & 15);
    ushortT* dst = pack + (size_t)GATE_FRAGS * 8 + (size_t)i2 * 8;
    #pragma unroll
    for (int j = 0; j < 8; ++j) dst[j] = f2bf(Wn[(size_t)(k0 + j) * Hc + col]);
  }
}

// W*2 B-fragment (h-part rows 256..383 of gate g => kt slots 8..11)
__device__ __forceinline__ const bf16x8* wh_frag(const ushortT* pack, int g, int cw, int kf, int lane) {
  return (const bf16x8*)&pack[(size_t)(((g * 8 + cw) * 12 + (8 + kf)) * 64 + lane) * 8];
}

// ---------------- kernel 3: xg_gemm (32-row tiles, blocks [0,XB)) || stage+Hf ----
__global__ __launch_bounds__(256) void xg_stage_hf(
    const float* __restrict__ fmess, const int* __restrict__ submess,
    const ushortT* __restrict__ pack,
    const float* __restrict__ bi, const float* __restrict__ bo,
    const float* __restrict__ bu, const float* __restrict__ bfb,
    ushortT* __restrict__ Xg,
    const float* __restrict__ h_in, const float* __restrict__ c_in,
    const int* __restrict__ mark,
    float* __restrict__ h_out, float* __restrict__ c_out,
    ushortT* __restrict__ HCF,
    int M, int S, int XB)
{
  __shared__ __align__(16) ushortT xs[32 * ZP2];   // 16896 B; reused for outputs
  __shared__ int aux[32];
  const int t = threadIdx.x;
  const int w = t >> 6, lane = t & 63, lg = lane >> 4, cl = lane & 15;

  if ((int)blockIdx.x < XB) {
    // ---- xg part: 32 rows, 2 M-subtiles per wave (B-frag reuse x2) ----
    const int row0 = blockIdx.x * 32;
    if (t < 32) aux[t] = (row0 + t < S) ? submess[row0 + t] : -1;
    __syncthreads();
    #pragma unroll
    for (int rr = 0; rr < 2; ++rr) {
      int r = (t >> 4) + rr * 16, cp = t & 15;
      int ms = aux[r];
      const float4* xr = (ms >= 0) ? (const float4*)(fmess + (size_t)ms * INc) : nullptr;
      #pragma unroll
      for (int q = 0; q < 4; ++q) {
        int slot = cp + q * 16;
        float4 v;
        if (xr) v = xr[slot]; else { v.x = v.y = v.z = v.w = 0.f; }
        *(us4*)&xs[r * ZP2 + slot * 4] = f2bf4(v);
      }
    }
    __syncthreads();

    f32x4 acc0[8], acc1[8];
    #pragma unroll
    for (int i = 0; i < 8; ++i) {
      acc0[i] = (f32x4){0.f, 0.f, 0.f, 0.f};
      acc1[i] = (f32x4){0.f, 0.f, 0.f, 0.f};
    }
    const ushortT* zrA = &xs[cl * ZP2 + lg * 8];
    const ushortT* zrB = &xs[(16 + cl) * ZP2 + lg * 8];
    #pragma unroll
    for (int kt = 0; kt < 8; ++kt) {
      bf16x8 a0 = *(const bf16x8*)&zrA[kt * 32];
      bf16x8 a1 = *(const bf16x8*)&zrB[kt * 32];
      #pragma unroll
      for (int c = 0; c < 8; ++c) {
        bf16x8 b = *(const bf16x8*)&pack[(size_t)(((w * 8 + c) * 12 + kt) * 64 + lane) * 8];
        acc0[c] = __builtin_amdgcn_mfma_f32_16x16x32_bf16(a0, b, acc0[c], 0, 0, 0);
        acc1[c] = __builtin_amdgcn_mfma_f32_16x16x32_bf16(a1, b, acc1[c], 0, 0, 0);
      }
    }
    __syncthreads();   // xs input reads done; reuse as output staging [16][XOP]
    const float* bias = (w == 0) ? bi : (w == 1) ? bo : (w == 2) ? bu : bfb;
    #pragma unroll
    for (int mt = 0; mt < 2; ++mt) {
      #pragma unroll
      for (int c = 0; c < 8; ++c) {
        int col = c * 16 + cl;
        float bv = bias[col];
        #pragma unroll
        for (int reg = 0; reg < 4; ++reg) {
          float v = (mt ? acc1[c][reg] : acc0[c][reg]) + bv;
          xs[(lg * 4 + reg) * XOP + w * 128 + col] = f2bf(v);
        }
      }
      __syncthreads();
      {
        int r = t >> 4, cc = t & 15;
        int s = row0 + mt * 16 + r;
        if (s < S) {
          const ushortT* src = &xs[r * XOP + cc * 32];
          ushortT* dst = &Xg[(size_t)s * 512 + cc * 32];
          *(us8*)&dst[0]  = *(const us8*)&src[0];
          *(us8*)&dst[8]  = *(const us8*)&src[8];
          *(us8*)&dst[16] = *(const us8*)&src[16];
          *(us8*)&dst[24] = *(const us8*)&src[24];
        }
      }
      __syncthreads();
    }
    return;
  }

  // ---- stage + Hf tile part: 16 rows; writes interleaved HCF ----
  ushortT* zh = xs;   // [16][HP]
  int* mk = aux;
  const int row0 = (blockIdx.x - XB) * 16;

  if (blockIdx.x == XB && t < 48) {    // zero DUMMY row (M+S): 384 ushorts = 48 us8
    us8 z;
    #pragma unroll
    for (int e = 0; e < 8; ++e) z[e] = 0;
    *(us8*)&HCF[(size_t)(M + S) * HCS + t * 8] = z;
  }
  if (t < 16) mk[t] = (row0 + t < M) ? mark[row0 + t] : 0;   // >=0 => skip
  __syncthreads();
  {
    int r = t >> 4, cp = t & 15;
    int j = row0 + r;
    us8 hz;
    #pragma unroll
    for (int e = 0; e < 8; ++e) hz[e] = 0;
    if (j < M && mk[r] < 0) {
      const float4* h4 = (const float4*)(h_in + (size_t)j * Hc);
      const float4* c4 = (const float4*)(c_in + (size_t)j * Hc);
      float4 a0 = h4[cp * 2], a1 = h4[cp * 2 + 1];
      float4 b0 = c4[cp * 2], b1 = c4[cp * 2 + 1];
      nt_store4(&a0.x, h_out + (size_t)j * Hc + cp * 8);
      nt_store4(&a1.x, h_out + (size_t)j * Hc + cp * 8 + 4);
      nt_store4(&b0.x, c_out + (size_t)j * Hc + cp * 8);
      nt_store4(&b1.x, c_out + (size_t)j * Hc + cp * 8 + 4);
      us8 h8 = f2bf8(a0, a1);
      *(us8*)&HCF[(size_t)j * HCS + cp * 8] = h8;
      *(us8*)&HCF[(size_t)j * HCS + 128 + cp * 8] = f2bf8(b0, b1);
      hz = h8;
    }
    *(us8*)&zh[r * HP + cp * 8] = hz;
  }
  __syncthreads();

  f32x4 acc0 = (f32x4){0.f,0.f,0.f,0.f}, acc1 = acc0;
  const ushortT* zr = &zh[cl * HP + lg * 8];
  #pragma unroll
  for (int kf = 0; kf < 4; ++kf) {
    bf16x8 a = *(const bf16x8*)&zr[kf * 32];
    acc0 = __builtin_amdgcn_mfma_f32_16x16x32_bf16(a, *wh_frag(pack, 3, w*2+0, kf, lane), acc0, 0, 0, 0);
    acc1 = __builtin_amdgcn_mfma_f32_16x16x32_bf16(a, *wh_frag(pack, 3, w*2+1, kf, lane), acc1, 0, 0, 0);
  }
  __syncthreads();   // zh A-frag reads done; reuse for Hf roundtrip
  #pragma unroll
  for (int half = 0; half < 2; ++half) {
    int col = (w * 2 + half) * 16 + cl;
    f32x4 a_ = half ? acc1 : acc0;
    #pragma unroll
    for (int reg = 0; reg < 4; ++reg)
      zh[(lg * 4 + reg) * HP + col] = f2bf(a_[reg]);
  }
  __syncthreads();
  {
    int r = t >> 4, cp = t & 15;
    if (row0 + r < M && mk[r] < 0)
      *(us8*)&HCF[(size_t)(row0 + r) * HCS + 256 + cp * 8] = *(const us8*)&zh[r * HP + cp * 8];
  }
}

// ---- kernels 4/5: LSTM step over interleaved HCF shadows ----
template<int MODE>
__global__ __launch_bounds__(256) void lstm8(
    const int* __restrict__ submess, const int* __restrict__ bgraph,
    const int* __restrict__ mark,
    ushortT* HCF,
    const ushortT* __restrict__ Xg, const ushortT* __restrict__ pack,
    ushortT* hsumNS, ushortT* cpartNS,
    float* __restrict__ dstH, float* __restrict__ dstC, int S, int M)
{
  __shared__ __align__(16) ushortT zs[16 * HSP];
  __shared__ __align__(16) ushortT pih[16 * EPH];
  __shared__ __align__(16) ushortT poh[16 * EPH];
  __shared__ __align__(16) ushortT puh[16 * EPH];
  __shared__ int nbj[16][Kc];
  __shared__ int msrow[16];

  const int t = threadIdx.x;
  const int row0 = blockIdx.x * 16;
  const int DUMMY = M + S;

  if (t < 128) {
    int r = t >> 3, k = t & 7;
    int s = row0 + r;
    int ms = (s < S) ? submess[s] : -1;
    if (k == 0) msrow[r] = ms;
    int j = DUMMY;
    if (ms >= 0) {
      int jj = bgraph[(size_t)ms * Kc + k];
      int m = mark[jj];
      j = (MODE == 0) ? (m >= 0 ? DUMMY : jj) : (m >= 0 ? M + m : DUMMY);
    }
    nbj[r][k] = j;
  }
  __syncthreads();

  {
    int r = t >> 4, cp = t & 15;
    int spos = row0 + r;
    float sum[8] = {0.f,0.f,0.f,0.f,0.f,0.f,0.f,0.f};
    if (MODE == 1 && spos < S) {
      us8 hs = *(const us8*)&hsumNS[(size_t)spos * Hc + cp * 8];
      #pragma unroll
      for (int e = 0; e < 8; ++e) sum[e] = bf2f(hs[e]);
    }
    #pragma unroll
    for (int k = 0; k < Kc; ++k) {
      int j = nbj[r][k];
      us8 v = *(const us8*)&HCF[(size_t)j * HCS + cp * 8];
      #pragma unroll
      for (int e = 0; e < 8; ++e) sum[e] += bf2f(v[e]);
    }
    us8 o8;
    #pragma unroll
    for (int e = 0; e < 8; ++e) o8[e] = f2bf(sum[e]);
    *(us8*)&zs[r * HSP + cp * 8] = o8;
    if (MODE == 0 && spos < S)
      *(us8*)&hsumNS[(size_t)spos * Hc + cp * 8] = o8;
  }
  __syncthreads();

  const int w = t >> 6, lane = t & 63, lg = lane >> 4, cl = lane & 15;

  f32x4 acc[6];
  #pragma unroll
  for (int i = 0; i < 6; ++i) acc[i] = (f32x4){0.f, 0.f, 0.f, 0.f};
  const ushortT* zrow = &zs[cl * HSP + lg * 8];
  #pragma unroll
  for (int kf = 0; kf < 4; ++kf) {
    bf16x8 a = *(const bf16x8*)&zrow[kf * 32];
    #pragma unroll
    for (int g = 0; g < 3; ++g)
      #pragma unroll
      for (int half = 0; half < 2; ++half)
        acc[g * 2 + half] = __builtin_amdgcn_mfma_f32_16x16x32_bf16(
            a, *wh_frag(pack, g, w * 2 + half, kf, lane), acc[g * 2 + half], 0, 0, 0);
  }

  #pragma unroll
  for (int half = 0; half < 2; ++half) {
    int col = (w * 2 + half) * 16 + cl;
    #pragma unroll
    for (int reg = 0; reg < 4; ++reg) {
      int row = lg * 4 + reg;
      pih[row * EPH + col] = f2bf(acc[0 + half][reg]);
      poh[row * EPH + col] = f2bf(acc[2 + half][reg]);
      puh[row * EPH + col] = f2bf(acc[4 + half][reg]);
    }
  }
  __syncthreads();

  {
    int r = t >> 4, cc = t & 15;
    int ms = msrow[r];
    int spos = row0 + r;
    const ushortT* xgr = Xg + (size_t)spos * 512 + cc * 8;
    us8 xi8 = *(const us8*)&xgr[0];
    us8 xo8 = *(const us8*)&xgr[128];
    us8 xu8 = *(const us8*)&xgr[256];
    us8 xf8 = *(const us8*)&xgr[384];
    us8 pi8 = *(const us8*)&pih[r * EPH + cc * 8];
    us8 po8 = *(const us8*)&poh[r * EPH + cc * 8];
    us8 pu8 = *(const us8*)&puh[r * EPH + cc * 8];
    float fx[8], ovv[8], iu[8], cn[8];
    #pragma unroll
    for (int e = 0; e < 8; ++e) {
      float iv = fsig(bf2f(xi8[e]) + bf2f(pi8[e]));
      float uv = ftanh(bf2f(xu8[e]) + bf2f(pu8[e]));
      ovv[e] = fsig(bf2f(xo8[e]) + bf2f(po8[e]));
      fx[e] = bf2f(xf8[e]);
      iu[e] = iv * uv;
      cn[e] = 0.f;
    }
    #pragma unroll
    for (int k = 0; k < Kc; ++k) {
      int j = nbj[r][k];
      us8 hf8 = *(const us8*)&HCF[(size_t)j * HCS + 256 + cc * 8];
      us8 cn8 = *(const us8*)&HCF[(size_t)j * HCS + 128 + cc * 8];
      #pragma unroll
      for (int e = 0; e < 8; ++e)
        cn[e] = fmaf(fsig(fx[e] + bf2f(hf8[e])), bf2f(cn8[e]), cn[e]);
    }
    float cacc[8];
    if (MODE == 1 && spos < S) {
      us8 cp8 = *(const us8*)&cpartNS[(size_t)spos * Hc + cc * 8];
      #pragma unroll
      for (int e = 0; e < 8; ++e) cacc[e] = iu[e] + cn[e] + bf2f(cp8[e]);
    } else {
      #pragma unroll
      for (int e = 0; e < 8; ++e) cacc[e] = iu[e] + cn[e];
    }
    float hv[8];
    #pragma unroll
    for (int e = 0; e < 8; ++e) hv[e] = ovv[e] * ftanh(cacc[e]);

    if (MODE == 0) {
      us8 h8, c8, cn16;
      #pragma unroll
      for (int e = 0; e < 8; ++e) {
        h8[e] = (spos < S) ? f2bf(hv[e]) : (ushortT)0;
        c8[e] = f2bf(cacc[e]);
        cn16[e] = f2bf(cn[e]);
      }
      if (spos < S) {
        *(us8*)&HCF[(size_t)(M + spos) * HCS + cc * 8] = h8;
        *(us8*)&HCF[(size_t)(M + spos) * HCS + 128 + cc * 8] = c8;
        *(us8*)&cpartNS[(size_t)spos * Hc + cc * 8] = cn16;
      }
      *(us8*)&zs[r * HSP + cc * 8] = h8;
    } else {
      if (ms >= 0) {
        float* dh = dstH + (size_t)ms * Hc + cc * 8;
        float* dc = dstC + (size_t)ms * Hc + cc * 8;
        *(float4*)&dh[0] = *(float4*)&hv[0];
        *(float4*)&dh[4] = *(float4*)&hv[4];
        nt_store4(&cacc[0], &dc[0]);
        nt_store4(&cacc[4], &dc[4]);
      }
    }
  }

  if (MODE == 0) {
    // ---- fused Hf tail; stores via pih roundtrip -> HCF[M+sp].F ----
    __syncthreads();
    f32x4 a0 = (f32x4){0.f,0.f,0.f,0.f}, a1 = a0;
    const ushortT* zr2 = &zs[cl * HSP + lg * 8];
    #pragma unroll
    for (int kf = 0; kf < 4; ++kf) {
      bf16x8 a = *(const bf16x8*)&zr2[kf * 32];
      a0 = __builtin_amdgcn_mfma_f32_16x16x32_bf16(a, *wh_frag(pack, 3, w*2+0, kf, lane), a0, 0, 0, 0);
      a1 = __builtin_amdgcn_mfma_f32_16x16x32_bf16(a, *wh_frag(pack, 3, w*2+1, kf, lane), a1, 0, 0, 0);
    }
    #pragma unroll
    for (int half = 0; half < 2; ++half) {
      int col = (w * 2 + half) * 16 + cl;
      f32x4 a_ = half ? a1 : a0;
      #pragma unroll
      for (int reg = 0; reg < 4; ++reg)
        pih[(lg * 4 + reg) * EPH + col] = f2bf(a_[reg]);
    }
    __syncthreads();
    {
      int r = t >> 4, cp = t & 15;
      int sp = row0 + r;
      if (sp < S)
        *(us8*)&HCF[(size_t)(M + sp) * HCS + 256 + cp * 8] = *(const us8*)&pih[r * EPH + cp * 8];
    }
  }
}

// ---------------- kernel 6: node readout || zero non-sub node rows ----------------
__global__ __launch_bounds__(256) void readout_zero(
    const float* __restrict__ fnode, const int* __restrict__ agraph,
    const int* __restrict__ subnode, const float* __restrict__ h_out,
    const ushortT* __restrict__ HCF, const int* __restrict__ mark,
    const int* __restrict__ nmark,
    const ushortT* __restrict__ packWn, const float* __restrict__ bn,
    float* __restrict__ node_buf, int Nsub, int num_nodes, int NB, int ZB)
{
  __shared__ __align__(16) ushortT z2[16 * ZP2];
  __shared__ int orow[16];
  __shared__ int jn[16][Kc];

  const int t = threadIdx.x;

  if ((int)blockIdx.x >= NB) {
    long total = (long)num_nodes * 16;
    float zbuf[4] = {0.f, 0.f, 0.f, 0.f};
    for (long idx = (long)(blockIdx.x - NB) * 256 + t; idx < total; idx += (long)ZB * 256) {
      long v = idx >> 4;
      int cp = (int)(idx & 15);
      if (nmark[v] < 0) {
        nt_store4(zbuf, node_buf + (size_t)v * Hc + cp * 8);
        nt_store4(zbuf, node_buf + (size_t)v * Hc + cp * 8 + 4);
      }
    }
    return;
  }

  const int row0 = blockIdx.x * 16;
  if (t < 16) orow[t] = (row0 + t < Nsub) ? subnode[row0 + t] : -1;
  if (t >= 64 && t < 64 + 128) {
    int i = t - 64, r = i >> 3, k = i & 7;
    int v = row0 + r;
    int j = 0;
    if (v < Nsub) {
      j = agraph[(size_t)v * Kc + k];
      if (mark[j] >= 0) j = ~j;   // sub message: gather f32 from h_out
    }
    jn[r][k] = j;
  }
  {
    int r = t >> 4, cp = t & 15;
    int v = row0 + r;
    const float4* fr = (v < Nsub) ? (const float4*)(fnode + (size_t)v * Hc) : nullptr;
    float4 v0, v1; v0.x = v0.y = v0.z = v0.w = 0.f; v1 = v0;
    if (fr) { v0 = fr[cp]; v1 = fr[cp + 16]; }
    *(us4*)&z2[r * ZP2 + cp * 4] = f2bf4(v0);
    *(us4*)&z2[r * ZP2 + 64 + cp * 4] = f2bf4(v1);
  }
  __syncthreads();
  {
    int r = t >> 4, cp = t & 15;
    float sum[8] = {0.f,0.f,0.f,0.f,0.f,0.f,0.f,0.f};
    #pragma unroll
    for (int k = 0; k < Kc; ++k) {
      int je = jn[r][k];
      if (je < 0) {
        int j = ~je;
        float4 p0 = ((const float4*)(h_out + (size_t)j * Hc))[cp * 2];
        float4 p1 = ((const float4*)(h_out + (size_t)j * Hc))[cp * 2 + 1];
        sum[0] += p0.x; sum[1] += p0.y; sum[2] += p0.z; sum[3] += p0.w;
        sum[4] += p1.x; sum[5] += p1.y; sum[6] += p1.z; sum[7] += p1.w;
      } else {
        us8 v = *(const us8*)&HCF[(size_t)je * HCS + cp * 8];
        #pragma unroll
        for (int e = 0; e < 8; ++e) sum[e] += bf2f(v[e]);
      }
    }
    us8 o8;
    #pragma unroll
    for (int e = 0; e < 8; ++e) o8[e] = f2bf(sum[e]);
    *(us8*)&z2[r * ZP2 + Hc + cp * 8] = o8;
  }
  __syncthreads();

  const int w = t >> 6, lane = t & 63;
  const int lg = lane >> 4, cl = lane & 15;

  f32x4 acc0 = (f32x4){0.f,0.f,0.f,0.f};
  f32x4 acc1 = (f32x4){0.f,0.f,0.f,0.f};
  const ushortT* zr = &z2[cl * ZP2 + lg * 8];
  #pragma unroll
  for (int kt = 0; kt < 8; ++kt) {
    bf16x8 a = *(const bf16x8*)&zr[kt * 32];
    bf16x8 b0 = *(const bf16x8*)&packWn[(size_t)(((w * 2 + 0) * 8 + kt) * 64 + lane) * 8];
    bf16x8 b1 = *(const bf16x8*)&packWn[(size_t)(((w * 2 + 1) * 8 + kt) * 64 + lane) * 8];
    acc0 = __builtin_amdgcn_mfma_f32_16x16x32_bf16(a, b0, acc0, 0, 0, 0);
    acc1 = __builtin_amdgcn_mfma_f32_16x16x32_bf16(a, b1, acc1, 0, 0, 0);
  }
  __syncthreads();   // z2 A-frag reads done; reuse as f32 output buffer
  float* zf = (float*)z2;   // [16][132] f32
  #pragma unroll
  for (int half = 0; half < 2; ++half) {
    int col = (w * 2 + half) * 16 + cl;
    float bnv = bn[col];
    f32x4 a_ = half ? acc1 : acc0;
    #pragma unroll
    for (int reg = 0; reg < 4; ++reg)
      zf[(lg * 4 + reg) * 132 + col] = fmaxf(a_[reg] + bnv, 0.f);
  }
  __syncthreads();
  {
    int r = t >> 4, cc = t & 15;
    int o = orow[r];
    if (o >= 0) {
      float* dst = node_buf + (size_t)o * Hc + cc * 8;
      nt_store4(&zf[r * 132 + cc * 8], &dst[0]);
      nt_store4(&zf[r * 132 + cc * 8 + 4], &dst[4]);
    }
  }
}

// ---------------- launch ----------------
extern "C" void kernel_launch(void* const* d_in, const int* in_sizes, int n_in,
                              void* d_out, int out_size, void* d_ws, size_t ws_size,
                              hipStream_t stream) {
  const float* fnode   = (const float*)d_in[0];
  const float* fmess   = (const float*)d_in[1];
  const int*   agraph  = (const int*)d_in[2];
  const int*   bgraph  = (const int*)d_in[3];
  const float* h_in    = (const float*)d_in[4];
  const float* c_in    = (const float*)d_in[5];
  const int*   submess = (const int*)d_in[6];
  const int*   subnode = (const int*)d_in[7];
  const float* Wi = (const float*)d_in[9];
  const float* bi = (const float*)d_in[10];
  const float* Wo = (const float*)d_in[11];
  const float* bo = (const float*)d_in[12];
  const float* Wf = (const float*)d_in[13];
  const float* bf_ = (const float*)d_in[14];
  const float* Wu = (const float*)d_in[15];
  const float* bu = (const float*)d_in[16];
  const float* Wn = (const float*)d_in[17];
  const float* bn = (const float*)d_in[18];

  const int S    = in_sizes[6];
  const int Nsub = in_sizes[2] / Kc;
  const int M    = in_sizes[4] / Hc;
  const int num_nodes = out_size / Hc - 2 * M;

  float* node_buf = (float*)d_out;
  float* h_out = node_buf + (size_t)num_nodes * Hc;
  float* c_out = h_out + (size_t)M * Hc;

  const int lblocks = (S + 15) / 16;

  // ws: mark[M] | nmark[num_nodes] | pack | HCF[(M+S+1)*384] | Xg[S*512]
  int* mark = (int*)d_ws;
  size_t off = (((size_t)M * sizeof(int)) + 255) & ~(size_t)255;
  int* nmark = (int*)((char*)d_ws + off);
  off += (((size_t)num_nodes * sizeof(int)) + 255) & ~(size_t)255;
  ushortT* pack = (ushortT*)((char*)d_ws + off);
  off += (((size_t)(GATE_FRAGS + WN_FRAGS) * 8 * sizeof(ushortT)) + 255) & ~(size_t)255;
  ushortT* HCF = (ushortT*)((char*)d_ws + off);
  off += (((size_t)(M + S + 1) * HCS * sizeof(ushortT)) + 255) & ~(size_t)255;
  ushortT* Xg = (ushortT*)((char*)d_ws + off);
  ushortT* packWn = pack + (size_t)GATE_FRAGS * 8;
  ushortT* cpartNS = (ushortT*)node_buf;
  ushortT* hsumNS  = cpartNS + (size_t)S * Hc;

  // 1. init marks
  int initN = (M > num_nodes) ? M : num_nodes;
  hipLaunchKernelGGL(marks_init, dim3((initN + 255) / 256), dim3(256), 0, stream,
                     mark, M, nmark, num_nodes);
  // 2. set marks || repack
  {
    int SB = (S + 255) / 256;
    int RB = (GATE_FRAGS + WN_FRAGS + 255) / 256;
    hipLaunchKernelGGL(set_repack, dim3(SB + RB), dim3(256), 0, stream,
                       submess, subnode, S, mark, nmark, Wi, Wo, Wu, Wf, Wn, pack, SB);
  }
  // 3. xg (32-row tiles) || stage+Hf tiles
  {
    int XB = (S + 31) / 32;
    int SB2 = (M + 15) / 16;
    hipLaunchKernelGGL(xg_stage_hf, dim3(XB + SB2), dim3(256), 0, stream,
                       fmess, submess, pack, bi, bo, bu, bf_, Xg,
                       h_in, c_in, mark, h_out, c_out, HCF,
                       M, S, XB);
  }
  // 4. iter 0 (fused Hf tail)
  hipLaunchKernelGGL(lstm8<0>, dim3(lblocks), dim3(256), 0, stream,
      submess, bgraph, mark, HCF, Xg, pack,
      hsumNS, cpartNS, h_out, c_out, S, M);
  // 5. iter 1
  hipLaunchKernelGGL(lstm8<1>, dim3(lblocks), dim3(256), 0, stream,
      submess, bgraph, mark, HCF, Xg, pack,
      hsumNS, cpartNS, h_out, c_out, S, M);
  // 6. readout || zero non-sub node rows
  {
    int NB = (Nsub + 15) / 16;
    int ZB = 512;
    hipLaunchKernelGGL(readout_zero, dim3(NB + ZB), dim3(256), 0, stream,
        fnode, agraph, subnode, h_out, HCF, mark, nmark, packWn, bn,
        node_buf, Nsub, num_nodes, NB, ZB);
  }
}